// Round 2
// baseline (147.783 us; speedup 1.0000x reference)
//
#include <hip/hip_runtime.h>
#include <hip/hip_bf16.h>

// Problem: Nav_64939905516231 (VIN-style value iteration), MI355X gfx950.
// B=64, H=W=64, dim_h=150, n_hat=8, n_act=4, K=10.
// All float inputs/outputs are float32 (reference dtype); maze is int32.
// Inputs: maze[64,64,64], emb[3,2], encode_w[150,2,5,5], encode_b[150],
//         r_w[150], q_w[8,1,5,5], w[8,1,5,5], fc_w[4,8].
// Output: [64,64,64,4] float32.
//
// Algebraic collapses (exact, linear):
//   r  = conv5x5(m, W_eff) + b_eff,  W_eff = sum_c r_w[c]*encode_w[c]
//   q_t = q0 + conv5x5(v_{t-1}, w),  q0 = conv5x5(r, q_w), v = max_c q
// State per step is only v [B,H,W]. Final q fused into the 8->4 projection.

#define BB 64
#define HH 64
#define WW 64
#define NHAT 8
#define DIMH 150

// ---------------- prep: T[4][25] tap table + b_eff ----------------
__global__ __launch_bounds__(128) void prep_kernel(
    const float* __restrict__ emb,
    const float* __restrict__ encode_w,
    const float* __restrict__ encode_b,
    const float* __restrict__ r_w,
    float* __restrict__ T, float* __restrict__ beff) {
  __shared__ float weff[2][25];
  int tid = threadIdx.x;
  if (tid < 50) {
    int i = tid / 25, k = tid % 25;
    float s = 0.f;
    for (int c = 0; c < DIMH; ++c)
      s += r_w[c] * encode_w[c * 50 + i * 25 + k];
    weff[i][k] = s;
  }
  if (tid == 64) {
    float s = 0.f;
    for (int c = 0; c < DIMH; ++c) s += r_w[c] * encode_b[c];
    *beff = s;
  }
  __syncthreads();
  if (tid < 100) {
    int val = tid / 25, k = tid % 25;
    float t = 0.f;
    if (val < 3)
      t = weff[0][k] * emb[val * 2 + 0] + weff[1][k] * emb[val * 2 + 1];
    T[val * 25 + k] = t;  // row 3 == 0 (zero-padding sentinel)
  }
}

// ---------------- r = table-conv over maze ----------------
__global__ __launch_bounds__(256) void r_kernel(
    const int* __restrict__ maze, const float* __restrict__ T,
    const float* __restrict__ beff, float* __restrict__ r) {
  __shared__ float Ts[4][25];
  __shared__ unsigned char mz[8][68];
  int tid = threadIdx.x;
  if (tid < 100) Ts[tid / 25][tid % 25] = T[tid];
  int b = blockIdx.y;
  int y0 = blockIdx.x * 4;
  for (int idx = tid; idx < 8 * 68; idx += 256) {
    int ry = idx / 68, rx = idx % 68;
    int gy = y0 - 2 + ry, gx = rx - 2;
    unsigned char v = 3;  // out-of-bounds -> T row 3 (zeros)
    if (gy >= 0 && gy < HH && gx >= 0 && gx < WW)
      v = (unsigned char)maze[(b * HH + gy) * WW + gx];
    mz[ry][rx] = v;
  }
  __syncthreads();
  int ly = tid >> 6, x = tid & 63, gy = y0 + ly;
  float s = *beff;
#pragma unroll
  for (int ky = 0; ky < 5; ++ky)
#pragma unroll
    for (int kx = 0; kx < 5; ++kx)
      s += Ts[mz[ly + ky][x + kx]][ky * 5 + kx];
  r[(b * HH + gy) * WW + x] = s;
}

// ---------------- q0 = conv5x5(r, q_w), v0 = max_c q0 ----------------
__global__ __launch_bounds__(256) void q0_kernel(
    const float* __restrict__ r, const float* __restrict__ q_w,
    float* __restrict__ q0, float* __restrict__ v0) {
  __shared__ float rt[8][68];
  __shared__ float qw[NHAT][25];
  int tid = threadIdx.x;
  if (tid < NHAT * 25) qw[tid / 25][tid % 25] = q_w[tid];
  int b = blockIdx.y;
  int y0 = blockIdx.x * 4;
  for (int idx = tid; idx < 8 * 68; idx += 256) {
    int ry = idx / 68, rx = idx % 68;
    int gy = y0 - 2 + ry, gx = rx - 2;
    float v = 0.f;
    if (gy >= 0 && gy < HH && gx >= 0 && gx < WW) v = r[(b * HH + gy) * WW + gx];
    rt[ry][rx] = v;
  }
  __syncthreads();
  int ly = tid >> 6, x = tid & 63, gy = y0 + ly;
  float acc[NHAT];
#pragma unroll
  for (int c = 0; c < NHAT; ++c) acc[c] = 0.f;
#pragma unroll
  for (int k = 0; k < 25; ++k) {
    float rv = rt[ly + k / 5][x + k % 5];
#pragma unroll
    for (int c = 0; c < NHAT; ++c) acc[c] += qw[c][k] * rv;
  }
  float vmax = acc[0];
#pragma unroll
  for (int c = 1; c < NHAT; ++c) vmax = fmaxf(vmax, acc[c]);
  float4* q0p = (float4*)&q0[(size_t)((b * HH + gy) * WW + x) * NHAT];
  q0p[0] = make_float4(acc[0], acc[1], acc[2], acc[3]);
  q0p[1] = make_float4(acc[4], acc[5], acc[6], acc[7]);
  v0[(b * HH + gy) * WW + x] = vmax;
}

// ---------------- step: v_out = max_c (q0 + conv5x5(v_in, w)) ----------------
__global__ __launch_bounds__(256) void step_kernel(
    const float* __restrict__ vin, const float* __restrict__ q0,
    const float* __restrict__ w, float* __restrict__ vout) {
  __shared__ float vt[8][68];
  __shared__ float wl[NHAT][25];
  int tid = threadIdx.x;
  if (tid < NHAT * 25) wl[tid / 25][tid % 25] = w[tid];
  int b = blockIdx.y;
  int y0 = blockIdx.x * 4;
  for (int idx = tid; idx < 8 * 68; idx += 256) {
    int ry = idx / 68, rx = idx % 68;
    int gy = y0 - 2 + ry, gx = rx - 2;
    float v = 0.f;
    if (gy >= 0 && gy < HH && gx >= 0 && gx < WW) v = vin[(b * HH + gy) * WW + gx];
    vt[ry][rx] = v;
  }
  __syncthreads();
  int ly = tid >> 6, x = tid & 63, gy = y0 + ly;
  const float4* q0p = (const float4*)&q0[(size_t)((b * HH + gy) * WW + x) * NHAT];
  float4 qa = q0p[0], qb = q0p[1];
  float acc[NHAT] = {qa.x, qa.y, qa.z, qa.w, qb.x, qb.y, qb.z, qb.w};
#pragma unroll
  for (int k = 0; k < 25; ++k) {
    float vv = vt[ly + k / 5][x + k % 5];
#pragma unroll
    for (int c = 0; c < NHAT; ++c) acc[c] += wl[c][k] * vv;
  }
  float vmax = acc[0];
#pragma unroll
  for (int c = 1; c < NHAT; ++c) vmax = fmaxf(vmax, acc[c]);
  vout[(b * HH + gy) * WW + x] = vmax;
}

// ---------------- final: out = (q0 + conv5x5(v9, w)) @ fc_w^T ----------------
__global__ __launch_bounds__(256) void out_kernel(
    const float* __restrict__ vin, const float* __restrict__ q0,
    const float* __restrict__ w, const float* __restrict__ fc_w,
    float* __restrict__ out) {
  __shared__ float vt[8][68];
  __shared__ float wl[NHAT][25];
  __shared__ float fc[4][NHAT];
  int tid = threadIdx.x;
  if (tid < NHAT * 25) wl[tid / 25][tid % 25] = w[tid];
  if (tid >= 224 && tid < 224 + 32) {
    int a = (tid - 224) / NHAT, c = (tid - 224) % NHAT;
    fc[a][c] = fc_w[a * NHAT + c];
  }
  int b = blockIdx.y;
  int y0 = blockIdx.x * 4;
  for (int idx = tid; idx < 8 * 68; idx += 256) {
    int ry = idx / 68, rx = idx % 68;
    int gy = y0 - 2 + ry, gx = rx - 2;
    float v = 0.f;
    if (gy >= 0 && gy < HH && gx >= 0 && gx < WW) v = vin[(b * HH + gy) * WW + gx];
    vt[ry][rx] = v;
  }
  __syncthreads();
  int ly = tid >> 6, x = tid & 63, gy = y0 + ly;
  const float4* q0p = (const float4*)&q0[(size_t)((b * HH + gy) * WW + x) * NHAT];
  float4 qa = q0p[0], qb = q0p[1];
  float acc[NHAT] = {qa.x, qa.y, qa.z, qa.w, qb.x, qb.y, qb.z, qb.w};
#pragma unroll
  for (int k = 0; k < 25; ++k) {
    float vv = vt[ly + k / 5][x + k % 5];
#pragma unroll
    for (int c = 0; c < NHAT; ++c) acc[c] += wl[c][k] * vv;
  }
  float4 o;
  float* op = &o.x;
#pragma unroll
  for (int a = 0; a < 4; ++a) {
    float s = 0.f;
#pragma unroll
    for (int c = 0; c < NHAT; ++c) s += fc[a][c] * acc[c];
    op[a] = s;
  }
  size_t base = (size_t)((b * HH + gy) * WW + x) * 4;
  *reinterpret_cast<float4*>(&out[base]) = o;
}

extern "C" void kernel_launch(void* const* d_in, const int* in_sizes, int n_in,
                              void* d_out, int out_size, void* d_ws, size_t ws_size,
                              hipStream_t stream) {
  const int* maze = (const int*)d_in[0];
  const float* emb = (const float*)d_in[1];
  const float* encode_w = (const float*)d_in[2];
  const float* encode_b = (const float*)d_in[3];
  const float* r_w = (const float*)d_in[4];
  const float* q_w = (const float*)d_in[5];
  const float* w = (const float*)d_in[6];
  const float* fc_w = (const float*)d_in[7];
  float* out = (float*)d_out;

  const int NPIX = BB * HH * WW;  // 262144
  float* wsf = (float*)d_ws;
  float* T = wsf;                 // 100 floats (+pad)
  float* beff = wsf + 100;        // 1 float
  float* r = wsf + 128;           // NPIX
  float* q0 = r + NPIX;           // NPIX*8
  float* vA = q0 + (size_t)NPIX * NHAT;  // NPIX
  float* vB = vA + NPIX;                 // NPIX

  dim3 grid(16, BB);  // 16 row-groups of 4 rows, 64 images
  prep_kernel<<<1, 128, 0, stream>>>(emb, encode_w, encode_b, r_w, T, beff);
  r_kernel<<<grid, 256, 0, stream>>>(maze, T, beff, r);
  q0_kernel<<<grid, 256, 0, stream>>>(r, q_w, q0, vA);
  float* vin = vA;
  float* vout = vB;
  for (int i = 1; i <= 9; ++i) {  // v1..v9
    step_kernel<<<grid, 256, 0, stream>>>(vin, q0, w, vout);
    float* t = vin; vin = vout; vout = t;
  }
  out_kernel<<<grid, 256, 0, stream>>>(vin, q0, w, fc_w, out);
}